// Round 7
// baseline (30.846 us; speedup 1.0000x reference)
//
#include <hip/hip_runtime.h>

// NeuralPonds: flavor = int(abs(np-pairwise-sum over d_model)) % 10000,
// out[token] = tables[pond[token], flavor]  (row of 1024 f32)
//
// Bit-exact numpy pairwise sum (verified on HW, absmax 0.0): 64 sequential
// chains r[b][j] = sum_k a[b*128 + j + 8k] (numpy accumulation order)
// combined by a balanced binary tree == 64-lane shfl_xor butterfly
// (masks 1,2,4 = within-block j-tree; 8,16,32 = across-block b-tree).
//
// Ladder: R1 fused 1tok/wave 30.1 | R2 +LDS 30.0 | R3 split 27.8 (best) |
// R4 strided k1 29.4 | R5 fence-not-barrier 28.0 | R6 persistent loop 29.1.
//
// R7: wave-autonomous batched fusion — 4 tokens/wave, all 16 ctx float4
// loads issued upfront (16KB in flight/wave), per-token pipeline
// {transpose -> fence -> reduce -> gather+nt-store} so token i's gather
// overlaps token i+1's reduce. One launch, no idxbuf round-trip.

#define POND_MOD 10000
#define D_MODEL  1024
#define PADDED   132            // 128 + 4 pad floats per 128-elem sub-block
#define REGION   (8 * PADDED)   // 1056 floats per transpose region
#define TPW      4              // tokens per wave

typedef float f32x4 __attribute__((ext_vector_type(4)));

__global__ __launch_bounds__(256) void np_fused4_kernel(
    const float* __restrict__ ctx,      // [ntok, 1024]
    const int*   __restrict__ pond,     // [ntok]
    const float* __restrict__ tables,   // [10*10000, 1024]
    float*       __restrict__ out,      // [ntok, 1024]
    int ntok)
{
    __shared__ float lds[4 * 2 * REGION];         // 4 waves x 2 regions = 33.8 KB

    const int lane = threadIdx.x & 63;
    const int wid  = threadIdx.x >> 6;
    const int wave = blockIdx.x * 4 + wid;
    const int base = wave * TPW;
    if (base >= ntok) return;
    const int cnt = (ntok - base) < TPW ? (ntok - base) : TPW;

    const int l31 = lane & 31;
    const int hb  = lane >> 5;
    const int b   = lane >> 3;
    const int j   = lane & 7;

    if (cnt == TPW) {
        // ---- fast path: issue ALL ctx loads upfront (16 x dwordx4) ----
        f32x4 v[TPW][4];
        #pragma unroll
        for (int i = 0; i < TPW; ++i) {
            const f32x4* row4 = (const f32x4*)(ctx + (size_t)(base + i) * D_MODEL);
            #pragma unroll
            for (int t = 0; t < 4; ++t)
                v[i][t] = __builtin_nontemporal_load(&row4[t * 64 + lane]);
        }
        int pd[TPW];
        #pragma unroll
        for (int i = 0; i < TPW; ++i)
            pd[i] = pond[base + i];

        #pragma unroll
        for (int i = 0; i < TPW; ++i) {
            // transpose token i into this wave's A/B region
            float* w = lds + (wid * 2 + (i & 1)) * REGION;
            #pragma unroll
            for (int t = 0; t < 4; ++t)
                *(f32x4*)(w + (2 * t + hb) * PADDED + 4 * l31) = v[i][t];

            // wave-local visibility (DS ops are wave-wide); no block barrier
            asm volatile("s_waitcnt lgkmcnt(0)" ::: "memory");
            __builtin_amdgcn_sched_barrier(0);

            // numpy-order chain: lane l = 8b + j sums a[b*128 + j + 8k]
            const float* rp = w + b * PADDED + j;
            float r = rp[0];
            #pragma unroll
            for (int k = 1; k < 16; ++k)
                r += rp[8 * k];

            // balanced-binary-tree combine == numpy pairwise tree
            #pragma unroll
            for (int m = 1; m < 64; m <<= 1)
                r += __shfl_xor(r, m, 64);

            const int flavor = ((int)fabsf(r)) % POND_MOD;
            const int idx    = pd[i] * POND_MOD + flavor;

            // gather + stream out now; overlaps next token's transpose/reduce
            const f32x4* src = (const f32x4*)(tables + (size_t)idx * D_MODEL);
            f32x4*       dst = (f32x4*)(out + (size_t)(base + i) * D_MODEL);
            #pragma unroll
            for (int k = 0; k < 4; ++k) {
                f32x4 g = src[k * 64 + lane];                        // hot: L2/L3
                __builtin_nontemporal_store(g, &dst[k * 64 + lane]);
            }
        }
    } else {
        // ---- tail path (ntok not divisible by 4): one token at a time ----
        for (int i = 0; i < cnt; ++i) {
            const int token = base + i;
            const f32x4* row4 = (const f32x4*)(ctx + (size_t)token * D_MODEL);
            const int pdv = pond[token];
            f32x4 v[4];
            #pragma unroll
            for (int t = 0; t < 4; ++t)
                v[t] = row4[t * 64 + lane];

            float* w = lds + (wid * 2 + (i & 1)) * REGION;
            #pragma unroll
            for (int t = 0; t < 4; ++t)
                *(f32x4*)(w + (2 * t + hb) * PADDED + 4 * l31) = v[t];

            asm volatile("s_waitcnt lgkmcnt(0)" ::: "memory");
            __builtin_amdgcn_sched_barrier(0);

            const float* rp = w + b * PADDED + j;
            float r = rp[0];
            #pragma unroll
            for (int k = 1; k < 16; ++k)
                r += rp[8 * k];
            #pragma unroll
            for (int m = 1; m < 64; m <<= 1)
                r += __shfl_xor(r, m, 64);

            const int flavor = ((int)fabsf(r)) % POND_MOD;
            const int idx    = pdv * POND_MOD + flavor;
            const f32x4* src = (const f32x4*)(tables + (size_t)idx * D_MODEL);
            f32x4*       dst = (f32x4*)(out + (size_t)token * D_MODEL);
            #pragma unroll
            for (int k = 0; k < 4; ++k)
                dst[k * 64 + lane] = src[k * 64 + lane];
        }
    }
}

extern "C" void kernel_launch(void* const* d_in, const int* in_sizes, int n_in,
                              void* d_out, int out_size, void* d_ws, size_t ws_size,
                              hipStream_t stream) {
    const float* ctx    = (const float*)d_in[0];   // context_vector [4,4096,1024] f32
    const int*   pond   = (const int*)d_in[1];     // pond_assignments [4,4096] i32
    const float* tables = (const float*)d_in[2];   // tables [10,10000,1024] f32
    float*       out    = (float*)d_out;           // [4,4096,1024] f32

    const int ntok   = in_sizes[1];                // 16384 tokens
    const int blocks = (ntok + 4 * TPW - 1) / (4 * TPW);   // 4 waves x 4 tokens

    np_fused4_kernel<<<blocks, 256, 0, stream>>>(ctx, pond, tables, out, ntok);
}

// Round 8
// 27.907 us; speedup vs baseline: 1.1053x; 1.1053x over previous
//
#include <hip/hip_runtime.h>

// NeuralPonds: flavor = int(abs(np-pairwise-sum over d_model)) % 10000,
// out[token] = tables[pond[token], flavor]  (row of 1024 f32)
//
// Bit-exact numpy pairwise sum (verified on HW, absmax 0.0): 64 sequential
// chains r[b][j] = sum_k a[b*128 + j + 8k] (numpy accumulation order)
// combined by a balanced binary tree == 64-lane shfl_xor butterfly.
//
// Final ladder: R1 fused 30.1 | R2 fused+LDS 30.0 | R3 split 27.8 (BEST) |
// R4 strided k1 29.4 | R5 fence k1 28.0 | R6 persistent 29.1 | R7 fused4 30.8.
// Conclusion: phase-split into a pure-read reduce kernel and a pure-write
// gather kernel is structurally optimal; fused variants pay ~8% for mixing
// gather/store traffic into the read stream. Residual over the ~23us
// traffic+launch floor is ramp/drain, unreachable by restructuring
// (4 experiments null/negative). This is R3 verbatim (measured 27.8us).

#define POND_MOD 10000
#define D_MODEL  1024
#define PADDED   132            // 128 + 4 pad floats per 128-elem sub-block
#define WAVE_LDS (8 * PADDED)

typedef float f32x4 __attribute__((ext_vector_type(4)));

__global__ __launch_bounds__(256) void np_flavor_kernel(
    const float* __restrict__ ctx,      // [ntok, 1024]
    const int*   __restrict__ pond,     // [ntok]
    int*         __restrict__ idxbuf,   // [ntok] combined pond*10000+flavor
    int ntok)
{
    __shared__ float lds[4 * WAVE_LDS];

    const int lane  = threadIdx.x & 63;
    const int wid   = threadIdx.x >> 6;
    const int token = blockIdx.x * 4 + wid;       // one wave per token
    const bool valid = token < ntok;
    const int  tok_safe = valid ? token : 0;

    // coalesced nontemporal load of the 4KB ctx row (streamed, never reused)
    const f32x4* row4 = (const f32x4*)(ctx + (size_t)tok_safe * D_MODEL);
    int pd = pond[tok_safe];
    f32x4 v[4];
    #pragma unroll
    for (int t = 0; t < 4; ++t)
        v[t] = __builtin_nontemporal_load(&row4[t * 64 + lane]);

    // transpose into padded LDS (2-way bank aliasing on read = free)
    // element e = 256t + 4l + s -> addr (2t + (l>>5))*132 + 4*(l&31) + s
    float* w = lds + wid * WAVE_LDS;
    const int l31 = lane & 31;
    const int hb  = lane >> 5;
    #pragma unroll
    for (int t = 0; t < 4; ++t)
        *(f32x4*)(w + (2 * t + hb) * PADDED + 4 * l31) = v[t];

    __syncthreads();

    // numpy-order chain: lane l = 8b + j sums a[b*128 + j + 8k], k=0..15
    const int b = lane >> 3;
    const int j = lane & 7;
    const float* rp = w + b * PADDED + j;
    float r = rp[0];
    #pragma unroll
    for (int k = 1; k < 16; ++k)
        r += rp[8 * k];

    // balanced-binary-tree combine across 64 lanes == numpy pairwise tree
    #pragma unroll
    for (int m = 1; m < 64; m <<= 1)
        r += __shfl_xor(r, m, 64);

    if (valid && lane == 0) {
        const int flavor = ((int)fabsf(r)) % POND_MOD;
        idxbuf[token] = pd * POND_MOD + flavor;
    }
}

__global__ __launch_bounds__(256) void np_gather_kernel(
    const float* __restrict__ tables,   // [10*10000, 1024]
    const int*   __restrict__ idxbuf,   // [ntok]
    float*       __restrict__ out,      // [ntok, 1024]
    int ntok)
{
    const int lane  = threadIdx.x & 63;
    const int wid   = threadIdx.x >> 6;
    const int token = blockIdx.x * 4 + wid;
    if (token >= ntok) return;

    const int idx = __builtin_amdgcn_readfirstlane(idxbuf[token]);
    const f32x4* src = (const f32x4*)(tables + (size_t)idx * D_MODEL);
    f32x4*       dst = (f32x4*)(out + (size_t)token * D_MODEL);

    #pragma unroll
    for (int k = 0; k < 4; ++k) {
        f32x4 v = src[k * 64 + lane];                        // hot rows: L2/L3
        __builtin_nontemporal_store(v, &dst[k * 64 + lane]); // pure stream out
    }
}

// fallback single kernel (ws too small) — R1-verified path
__global__ __launch_bounds__(256) void np_fused_kernel(
    const float* __restrict__ ctx, const int* __restrict__ pond,
    const float* __restrict__ tables, float* __restrict__ out, int ntok)
{
    const int lane  = threadIdx.x & 63;
    const int wid   = threadIdx.x >> 6;
    const int token = blockIdx.x * 4 + wid;
    if (token >= ntok) return;

    const float* row = ctx + (size_t)token * D_MODEL;
    const int b = lane >> 3, j = lane & 7;
    const float* p = row + b * 128 + j;
    float r = p[0];
    #pragma unroll
    for (int k = 1; k < 16; ++k) r += p[8 * k];
    #pragma unroll
    for (int m = 1; m < 64; m <<= 1) r += __shfl_xor(r, m, 64);

    const int flavor = ((int)fabsf(r)) % POND_MOD;
    const int pd = pond[token];
    const float4* src = (const float4*)(tables + ((size_t)pd * POND_MOD + flavor) * D_MODEL);
    float4*       dst = (float4*)(out + (size_t)token * D_MODEL);
    #pragma unroll
    for (int k = 0; k < 4; ++k) dst[k * 64 + lane] = src[k * 64 + lane];
}

extern "C" void kernel_launch(void* const* d_in, const int* in_sizes, int n_in,
                              void* d_out, int out_size, void* d_ws, size_t ws_size,
                              hipStream_t stream) {
    const float* ctx    = (const float*)d_in[0];
    const int*   pond   = (const int*)d_in[1];
    const float* tables = (const float*)d_in[2];
    float*       out    = (float*)d_out;

    const int ntok   = in_sizes[1];               // 16384 tokens
    const int blocks = (ntok + 3) / 4;

    if (ws_size >= (size_t)ntok * sizeof(int)) {
        int* idxbuf = (int*)d_ws;
        np_flavor_kernel<<<blocks, 256, 0, stream>>>(ctx, pond, idxbuf, ntok);
        np_gather_kernel<<<blocks, 256, 0, stream>>>(tables, idxbuf, out, ntok);
    } else {
        np_fused_kernel<<<blocks, 256, 0, stream>>>(ctx, pond, tables, out, ntok);
    }
}